// Round 6
// baseline (208.799 us; speedup 1.0000x reference)
//
#include <hip/hip_runtime.h>

typedef unsigned short u16;
typedef unsigned int u32;
typedef __attribute__((ext_vector_type(8))) short short8;
typedef __attribute__((ext_vector_type(4))) short short4v;
typedef __attribute__((ext_vector_type(4))) float f32x4;
typedef __attribute__((ext_vector_type(16))) float f32x16;

// ---- helpers ----
__device__ __forceinline__ u16 f2bf(float f) {
  u32 u = __float_as_uint(f);
  u = (u + 0x7fffu + ((u >> 16) & 1u)) >> 16;   // RNE
  return (u16)u;
}
__device__ __forceinline__ float bf2f(u16 h) {
  return __uint_as_float(((u32)h) << 16);
}
__device__ __forceinline__ void glds16(const u16* g, u16* l) {
  __builtin_amdgcn_global_load_lds(
      (const __attribute__((address_space(1))) void*)g,
      (__attribute__((address_space(3))) void*)l, 16, 0, 0);
}

// ---- RoPE cos/sin table: [2048][32] each ----
__global__ __launch_bounds__(256) void rope_tab_k(float* __restrict__ cosT,
                                                  float* __restrict__ sinT) {
  int idx = blockIdx.x * 256 + threadIdx.x;   // 65536
  int t = idx >> 5, i = idx & 31;
  float inv = powf(10000.0f, -(float)i / 32.0f);   // theta^(-2i/64)
  float ang = (float)t * inv;
  float s, c;
  sincosf(ang, &s, &c);
  cosT[idx] = c;
  sinT[idx] = s;
}

// ---- x fp32 -> bf16 ----
__global__ __launch_bounds__(256) void cvt_x_k(const float* __restrict__ x,
                                               u16* __restrict__ xb) {
  int i = blockIdx.x * 256 + threadIdx.x;   // 1048576 threads, 8 elems each
  int e = i * 8;
  float4 a = *(const float4*)(x + e);
  float4 b = *(const float4*)(x + e + 4);
  short8 o;
  o[0] = (short)f2bf(a.x); o[1] = (short)f2bf(a.y);
  o[2] = (short)f2bf(a.z); o[3] = (short)f2bf(a.w);
  o[4] = (short)f2bf(b.x); o[5] = (short)f2bf(b.y);
  o[6] = (short)f2bf(b.z); o[7] = (short)f2bf(b.w);
  *(short8*)(xb + e) = o;
}

// ---- W fp32 [k][n] -> bf16 transposed [n][k]; 4 weights stacked ----
__global__ __launch_bounds__(256) void wtrans_k(const float* __restrict__ W0,
                                                const float* __restrict__ W1,
                                                const float* __restrict__ W2,
                                                const float* __restrict__ W3,
                                                u16* __restrict__ wt) {
  __shared__ float tl[64][65];
  const float* W = (blockIdx.z == 0) ? W0 : (blockIdx.z == 1) ? W1
                  : (blockIdx.z == 2) ? W2 : W3;
  u16* out = wt + (size_t)blockIdx.z * 1024 * 1024;
  int k0 = blockIdx.x * 64, n0 = blockIdx.y * 64;
  int tid = threadIdx.x;
  int rr = tid >> 4, cc4 = (tid & 15) * 4;
#pragma unroll
  for (int p = 0; p < 4; ++p) {
    int r = rr + p * 16;
    float4 v = *(const float4*)(W + (size_t)(k0 + r) * 1024 + n0 + cc4);
    tl[r][cc4] = v.x; tl[r][cc4 + 1] = v.y; tl[r][cc4 + 2] = v.z; tl[r][cc4 + 3] = v.w;
  }
  __syncthreads();
#pragma unroll
  for (int p = 0; p < 4; ++p) {
    int rn = rr + p * 16;
    short4v o;
    o[0] = (short)f2bf(tl[cc4][rn]);     o[1] = (short)f2bf(tl[cc4 + 1][rn]);
    o[2] = (short)f2bf(tl[cc4 + 2][rn]); o[3] = (short)f2bf(tl[cc4 + 3][rn]);
    *(short4v*)(out + (size_t)(n0 + rn) * 1024 + k0 + cc4) = o;
  }
}

// ---- QKV GEMM: C[8192][3072] = xb @ [Wq|Wk|Wv]; epilogue scatters to
//      Q,K (B,H,T,64) and V transposed (B,H,64,T). m97 structure. ----
__global__ __launch_bounds__(256) void gemm_qkv_k(const u16* __restrict__ xb,
                                                  const u16* __restrict__ wt,
                                                  u16* __restrict__ Qb,
                                                  u16* __restrict__ Kb,
                                                  u16* __restrict__ Vt) {
  __shared__ __align__(16) u16 Ash[128][32];
  __shared__ __align__(16) u16 Bsh[128][32];
  int tid = threadIdx.x;
  int lane = tid & 63, w = tid >> 6;
  int wr = w >> 1, wc = w & 1;
  int l15 = lane & 15, g = lane >> 4;
  int row0 = blockIdx.x * 128;
  int ncol0 = blockIdx.y * 128;

  f32x4 zero = {0.f, 0.f, 0.f, 0.f};
  f32x4 acc[4][4];
#pragma unroll
  for (int m = 0; m < 4; ++m)
#pragma unroll
    for (int n = 0; n < 4; ++n) acc[m][n] = zero;

  int aRow = tid >> 2, aK = (tid & 3) * 8;
  const u16* aSrc0 = xb + (size_t)(row0 + aRow) * 1024 + aK;
  const u16* aSrc1 = xb + (size_t)(row0 + 64 + aRow) * 1024 + aK;
  const u16* bSrc0 = wt + (size_t)(ncol0 + aRow) * 1024 + aK;
  const u16* bSrc1 = wt + (size_t)(ncol0 + 64 + aRow) * 1024 + aK;
  u16* ldsA0 = &Ash[0][0] + tid * 8;
  u16* ldsA1 = &Ash[0][0] + 2048 + tid * 8;
  u16* ldsB0 = &Bsh[0][0] + tid * 8;
  u16* ldsB1 = &Bsh[0][0] + 2048 + tid * 8;

  for (int kt = 0; kt < 32; ++kt) {
    __syncthreads();
    glds16(aSrc0, ldsA0); glds16(aSrc1, ldsA1);
    glds16(bSrc0, ldsB0); glds16(bSrc1, ldsB1);
    aSrc0 += 32; aSrc1 += 32; bSrc0 += 32; bSrc1 += 32;
    __syncthreads();
    short8 af[4], bfr[4];
#pragma unroll
    for (int m = 0; m < 4; ++m) af[m] = *(const short8*)&Ash[wr * 64 + m * 16 + l15][g * 8];
#pragma unroll
    for (int n = 0; n < 4; ++n) bfr[n] = *(const short8*)&Bsh[wc * 64 + n * 16 + l15][g * 8];
#pragma unroll
    for (int m = 0; m < 4; ++m)
#pragma unroll
      for (int n = 0; n < 4; ++n)
        acc[m][n] = __builtin_amdgcn_mfma_f32_16x16x32_bf16(af[m], bfr[n], acc[m][n], 0, 0, 0);
  }

  int c0 = ncol0 + wc * 64;
  int which = c0 >> 10;        // uniform per block (0=Q,1=K,2=V)
  int rb = row0 + wr * 64;
#pragma unroll
  for (int m = 0; m < 4; ++m) {
    int r = rb + m * 16 + g * 4;
    int bb = r >> 11, t = r & 2047;
#pragma unroll
    for (int n = 0; n < 4; ++n) {
      int c = c0 + n * 16 + l15;
      int hh = (c & 1023) >> 6, d = c & 63;
      if (which == 2) {
        short4v o;
        o[0] = (short)f2bf(acc[m][n][0]); o[1] = (short)f2bf(acc[m][n][1]);
        o[2] = (short)f2bf(acc[m][n][2]); o[3] = (short)f2bf(acc[m][n][3]);
        *(short4v*)(Vt + ((size_t)((bb * 16 + hh) * 64 + d)) * 2048 + t) = o;
      } else {
        u16* dst = (which == 0 ? Qb : Kb) + ((size_t)((bb * 16 + hh) * 2048 + t)) * 64 + d;
        dst[0]   = f2bf(acc[m][n][0]);
        dst[64]  = f2bf(acc[m][n][1]);
        dst[128] = f2bf(acc[m][n][2]);
        dst[192] = f2bf(acc[m][n][3]);
      }
    }
  }
}

// ---- RoPE in-place on Q (x SCALE) and K ----
__global__ __launch_bounds__(256) void rope_k(u16* __restrict__ Qb, u16* __restrict__ Kb,
                                              const float* __restrict__ cosT,
                                              const float* __restrict__ sinT) {
  int i = blockIdx.x * 256 + threadIdx.x;   // 2097152
  u16* P; float sc; int j;
  if (i < 1048576) { P = Qb; sc = 0.03125f; j = i; }     // SCALE = 1024^-0.5
  else             { P = Kb; sc = 1.0f;     j = i - 1048576; }
  int e = j * 8;
  int d0 = e & 63;
  int t = (e >> 6) & 2047;
  short8 v = *(const short8*)(P + e);
  const float* cb = cosT + t * 32 + (d0 >> 1);
  const float* sb = sinT + t * 32 + (d0 >> 1);
  short8 o;
#pragma unroll
  for (int p = 0; p < 4; ++p) {
    float c = cb[p], s = sb[p];
    float a = bf2f((u16)v[2 * p]), b = bf2f((u16)v[2 * p + 1]);
    o[2 * p]     = (short)f2bf((a * c - b * s) * sc);
    o[2 * p + 1] = (short)f2bf((b * c + a * s) * sc);
  }
  *(short8*)(P + e) = o;
}

// ---- flash attention, non-causal, 32x32x16 MFMA path.
//      4 waves x 32 q-rows = 128 q/block; KV tile 64 double-buffered in LDS.
//      Swapped QK^T -> P cols=q in-lane; no max tracking (|logit| <= ~3,
//      softmax shift-invariant). P -> PV A-frags via v_permlane32_swap_b32.
//      Softmax denominator = mfma(P, ones) -> same acc layout as oa0/oa1
//      (lane-local normalize, zero epilogue shuffles); sums ride the idle
//      MFMA pipe instead of the binding VALU pipe. ----
__global__ __launch_bounds__(256) void attn_k(const u16* __restrict__ Q,
                                              const u16* __restrict__ K,
                                              const u16* __restrict__ Vt,
                                              u16* __restrict__ O) {
  __shared__ __align__(16) u16 KVs[2][2][4096];   // [buf][K/V][64 rows x 64], swizzled
  int bid = blockIdx.x;
  int head = (bid & 7) + ((bid >> 7) << 3);   // one head's 16 blocks -> one XCD
  int qt = (bid >> 3) & 15;
  int bb = head >> 4, hh = head & 15;
  const u16* Qh = Q + (size_t)head * 131072;
  const u16* Kh = K + (size_t)head * 131072;
  const u16* Vh = Vt + (size_t)head * 131072;
  int tid = threadIdx.x, lane = tid & 63, w = tid >> 6;
  int l31 = lane & 31, hi = lane >> 5;
  int t0 = qt * 128 + w * 32;

  // staging: thread covers 16B chunk; source col pre-swizzled so linear LDS
  // write + XOR-swizzled read match (chunk ^= row&7).
  int srow = tid >> 3;                       // 0..31
  int scol = ((tid & 7) ^ (srow & 7)) * 8;   // u16 units

  // Q B-fragments (col=q=l31, k = d = ks*16 + hi*8 + e)
  short8 qf[4];
#pragma unroll
  for (int ks = 0; ks < 4; ++ks)
    qf[ks] = *(const short8*)(Qh + (size_t)(t0 + l31) * 64 + ks * 16 + hi * 8);

  // loop-invariant LDS read lane offsets (u16): row=l31 (+bl*32), chunk=(j*2+hi)^(lane&7)
  const u16* lds0 = &KVs[0][0][0];
  const u16* rpp[4];
#pragma unroll
  for (int j = 0; j < 4; ++j)
    rpp[j] = lds0 + l31 * 64 + ((((j * 2 + hi) ^ (lane & 7))) << 3);

  f32x16 zz;
#pragma unroll
  for (int i = 0; i < 16; ++i) zz[i] = 0.f;
  f32x16 oa0 = zz, oa1 = zz, oa2 = zz;
  short8 ones8 = {16256, 16256, 16256, 16256, 16256, 16256, 16256, 16256}; // bf16 1.0 x8

  const u16* kp = Kh + srow * 64 + scol;
  const u16* vp = Vh + srow * 2048 + scol;
  u16* sK = &KVs[0][0][0] + tid * 8;
  u16* sV = &KVs[0][1][0] + tid * 8;

#define STAGE_AT(BO) do {                                                      \
    glds16(kp,         sK + (BO));                                             \
    glds16(kp + 2048,  sK + (BO) + 2048);                                      \
    glds16(vp,         sV + (BO));                                             \
    glds16(vp + 65536, sV + (BO) + 2048);                                      \
    kp += 4096; vp += 64;                                                      \
  } while (0)

#define ATT_TILE(OB) do {                                                      \
    _Pragma("unroll")                                                          \
    for (int bl = 0; bl < 2; ++bl) {                                           \
      f32x16 pb = zz;                                                          \
      __builtin_amdgcn_s_setprio(1);                                           \
      _Pragma("unroll")                                                        \
      for (int ks = 0; ks < 4; ++ks) {                                         \
        short8 kf = *(const short8*)(rpp[ks] + (OB) + bl * 2048);              \
        pb = __builtin_amdgcn_mfma_f32_32x32x16_bf16(kf, qf[ks], pb, 0, 0, 0); \
      }                                                                        \
      __builtin_amdgcn_s_setprio(0);                                           \
      _Pragma("unroll")                                                        \
      for (int r = 0; r < 16; ++r) pb[r] = __expf(pb[r]);                      \
      u32 pk8[8];                                                              \
      _Pragma("unroll")                                                        \
      for (int j = 0; j < 8; ++j)                                              \
        asm("v_cvt_pk_bf16_f32 %0, %1, %2"                                     \
            : "=v"(pk8[j]) : "v"(pb[2 * j]), "v"(pb[2 * j + 1]));              \
      _Pragma("unroll")                                                        \
      for (int kb = 0; kb < 2; ++kb) {                                         \
        u32 w0 = pk8[4 * kb + 0], w2 = pk8[4 * kb + 2];                        \
        u32 w1 = pk8[4 * kb + 1], w3 = pk8[4 * kb + 3];                        \
        asm("v_permlane32_swap_b32 %0, %1" : "+v"(w0), "+v"(w2));              \
        asm("v_permlane32_swap_b32 %0, %1" : "+v"(w1), "+v"(w3));              \
        union { u32 u[4]; short8 s; } pu;                                      \
        pu.u[0] = w0; pu.u[1] = w1; pu.u[2] = w2; pu.u[3] = w3;                \
        const int kss = bl * 2 + kb;                                           \
        short8 vf0 = *(const short8*)(rpp[kss] + (OB) + 4096);                 \
        short8 vf1 = *(const short8*)(rpp[kss] + (OB) + 4096 + 2048);          \
        __builtin_amdgcn_s_setprio(1);                                         \
        oa0 = __builtin_amdgcn_mfma_f32_32x32x16_bf16(pu.s, vf0, oa0, 0,0,0);  \
        oa1 = __builtin_amdgcn_mfma_f32_32x32x16_bf16(pu.s, vf1, oa1, 0,0,0);  \
        oa2 = __builtin_amdgcn_mfma_f32_32x32x16_bf16(pu.s, ones8, oa2, 0,0,0);\
        __builtin_amdgcn_s_setprio(0);                                         \
      }                                                                        \
    }                                                                          \
  } while (0)

  STAGE_AT(0);   // prologue: tile 0 -> buf0
  for (int it = 0; it < 16; ++it) {
    STAGE_AT(8192);   // next tile -> buf1
    asm volatile("s_waitcnt vmcnt(4)\ns_barrier" ::: "memory");
    ATT_TILE(0);
    asm volatile("s_barrier" ::: "memory");
    if (it < 15) {
      STAGE_AT(0);    // next tile -> buf0
      asm volatile("s_waitcnt vmcnt(4)\ns_barrier" ::: "memory");
    } else {
      asm volatile("s_waitcnt vmcnt(0)\ns_barrier" ::: "memory");
    }
    ATT_TILE(8192);
    asm volatile("s_barrier" ::: "memory");
  }
#undef STAGE_AT
#undef ATT_TILE

  // epilogue: normalize (denominator lane-local in oa2, same row layout),
  // write O (B,T,1024) bf16
  size_t obase = (size_t)(bb * 2048 + t0) * 1024 + hh * 64 + l31;
#pragma unroll
  for (int r = 0; r < 16; ++r) {
    int qr = (r & 3) + ((r >> 2) << 3) + (hi << 2);
    float ir = 1.0f / oa2[r];
    O[obase + (size_t)qr * 1024]      = f2bf(oa0[r] * ir);
    O[obase + (size_t)qr * 1024 + 32] = f2bf(oa1[r] * ir);
  }
}

// ---- output projection: out = Ob @ Wp + bp (fp32 out) ----
__global__ __launch_bounds__(256) void gemm_out_k(const u16* __restrict__ Ob,
                                                  const u16* __restrict__ wt,
                                                  const float* __restrict__ bp,
                                                  float* __restrict__ out) {
  __shared__ __align__(16) u16 Ash[128][32];
  __shared__ __align__(16) u16 Bsh[128][32];
  int tid = threadIdx.x;
  int lane = tid & 63, w = tid >> 6;
  int wr = w >> 1, wc = w & 1;
  int l15 = lane & 15, g = lane >> 4;
  int row0 = blockIdx.x * 128;
  int ncol0 = blockIdx.y * 128;

  f32x4 zero = {0.f, 0.f, 0.f, 0.f};
  f32x4 acc[4][4];
#pragma unroll
  for (int m = 0; m < 4; ++m)
#pragma unroll
    for (int n = 0; n < 4; ++n) acc[m][n] = zero;

  int aRow = tid >> 2, aK = (tid & 3) * 8;
  const u16* aSrc0 = Ob + (size_t)(row0 + aRow) * 1024 + aK;
  const u16* aSrc1 = Ob + (size_t)(row0 + 64 + aRow) * 1024 + aK;
  const u16* bSrc0 = wt + (size_t)(ncol0 + aRow) * 1024 + aK;
  const u16* bSrc1 = wt + (size_t)(ncol0 + 64 + aRow) * 1024 + aK;
  u16* ldsA0 = &Ash[0][0] + tid * 8;
  u16* ldsA1 = &Ash[0][0] + 2048 + tid * 8;
  u16* ldsB0 = &Bsh[0][0] + tid * 8;
  u16* ldsB1 = &Bsh[0][0] + 2048 + tid * 8;

  for (int kt = 0; kt < 32; ++kt) {
    __syncthreads();
    glds16(aSrc0, ldsA0); glds16(aSrc1, ldsA1);
    glds16(bSrc0, ldsB0); glds16(bSrc1, ldsB1);
    aSrc0 += 32; aSrc1 += 32; bSrc0 += 32; bSrc1 += 32;
    __syncthreads();
    short8 af[4], bfr[4];
#pragma unroll
    for (int m = 0; m < 4; ++m) af[m] = *(const short8*)&Ash[wr * 64 + m * 16 + l15][g * 8];
#pragma unroll
    for (int n = 0; n < 4; ++n) bfr[n] = *(const short8*)&Bsh[wc * 64 + n * 16 + l15][g * 8];
#pragma unroll
    for (int m = 0; m < 4; ++m)
#pragma unroll
      for (int n = 0; n < 4; ++n)
        acc[m][n] = __builtin_amdgcn_mfma_f32_16x16x32_bf16(af[m], bfr[n], acc[m][n], 0, 0, 0);
  }

  int c0 = ncol0 + wc * 64;
  int rb = row0 + wr * 64;
  float bn[4];
#pragma unroll
  for (int n = 0; n < 4; ++n) bn[n] = bp[c0 + n * 16 + l15];
#pragma unroll
  for (int m = 0; m < 4; ++m) {
    int r = rb + m * 16 + g * 4;
#pragma unroll
    for (int n = 0; n < 4; ++n) {
      int c = c0 + n * 16 + l15;
      out[(size_t)(r + 0) * 1024 + c] = acc[m][n][0] + bn[n];
      out[(size_t)(r + 1) * 1024 + c] = acc[m][n][1] + bn[n];
      out[(size_t)(r + 2) * 1024 + c] = acc[m][n][2] + bn[n];
      out[(size_t)(r + 3) * 1024 + c] = acc[m][n][3] + bn[n];
    }
  }
}

extern "C" void kernel_launch(void* const* d_in, const int* in_sizes, int n_in,
                              void* d_out, int out_size, void* d_ws, size_t ws_size,
                              hipStream_t stream) {
  const float* x  = (const float*)d_in[0];
  // d_in[1]=h, d_in[2]=w : unused by the reference computation
  const float* Wq = (const float*)d_in[3];
  const float* Wk = (const float*)d_in[4];
  const float* Wv = (const float*)d_in[5];
  const float* Wp = (const float*)d_in[6];
  const float* bp = (const float*)d_in[7];
  float* out = (float*)d_out;

  char* ws = (char*)d_ws;
  u16* xb   = (u16*)(ws);                    // 16.78 MB
  u16* wt   = (u16*)(ws + 16777216);         // 8.39 MB (Wq^T,Wk^T,Wv^T,Wp^T)
  u16* Qb   = (u16*)(ws + 25165824);         // 16.78 MB (B,H,T,64)
  u16* Kb   = (u16*)(ws + 41943040);         // 16.78 MB
  u16* Vt   = (u16*)(ws + 58720256);         // 16.78 MB (B,H,64,T)
  u16* Ob   = (u16*)(ws + 75497472);         // 16.78 MB (B,T,1024)
  float* cosT = (float*)(ws + 92274688);     // 256 KB
  float* sinT = (float*)(ws + 92536832);     // 256 KB  (total ~92.8 MB)

  rope_tab_k<<<256, 256, 0, stream>>>(cosT, sinT);
  cvt_x_k<<<4096, 256, 0, stream>>>(x, xb);
  dim3 tg(16, 16, 4);
  wtrans_k<<<tg, 256, 0, stream>>>(Wq, Wk, Wv, Wp, wt);
  dim3 g1(64, 24);
  gemm_qkv_k<<<g1, 256, 0, stream>>>(xb, wt, Qb, Kb, Vt);
  rope_k<<<8192, 256, 0, stream>>>(Qb, Kb, cosT, sinT);
  attn_k<<<1024, 256, 0, stream>>>(Qb, Kb, Vt, Ob);
  dim3 g2(64, 8);
  gemm_out_k<<<g2, 256, 0, stream>>>(Ob, wt + (size_t)3 * 1024 * 1024, bp, out);
}